// Round 3
// baseline (1692.249 us; speedup 1.0000x reference)
//
#include <hip/hip_runtime.h>
#include <hip/hip_fp16.h>

#define TT   2048
#define BB   64
#define II   16
#define HH   8
#define HIDN 64
#define GG   256   // 4*HIDN

typedef _Float16 h2 __attribute__((ext_vector_type(2)));
typedef _Float16 h8 __attribute__((ext_vector_type(8)));

__device__ __forceinline__ float fdot2(h2 a, h2 b, float c) {
    return __builtin_amdgcn_fdot2(a, b, c, false);
}
__device__ __forceinline__ float fast_sigmoid(float z) {
    return __builtin_amdgcn_rcpf(1.0f + __expf(-z));
}
__device__ __forceinline__ float fast_tanh(float z) {
    return fmaf(2.0f, __builtin_amdgcn_rcpf(1.0f + __expf(-2.0f * z)), -1.0f);
}

// ---------------- x -> f16 conversion (one-time, trivial) ----------------
__global__ void cvt_x_kernel(const float* __restrict__ x, _Float16* __restrict__ xh, int n4) {
    int i = blockIdx.x * blockDim.x + threadIdx.x;
    if (i < n4) {
        float4 v = ((const float4*)x)[i];
        ((h2*)xh)[2 * i]     = h2{ (_Float16)v.x, (_Float16)v.y };
        ((h2*)xh)[2 * i + 1] = h2{ (_Float16)v.z, (_Float16)v.w };
    }
}

// ---------------- main recurrent kernel: ONE WAVE PER CHAIN ----------------
// grid = BB*HH blocks x 64 threads. lane = hidden unit; each lane computes all
// 4 gate rows of its unit (no cross-lane gate exchange). h is exchanged via a
// 128B LDS buffer with wave-synchronous in-order ds ops -> ZERO barriers.
// Global stores (stage h, out) are fire-and-forget: no vmcnt drain on the
// critical path (this was the R2 bottleneck: __syncthreads forces
// s_waitcnt vmcnt(0) every step when gates span waves).
template <int STAGE, bool XF16>
__global__ __launch_bounds__(64)
void lstm_wave(const float* __restrict__ x,
               const _Float16* __restrict__ xh,
               const float* __restrict__ Wih,
               const float* __restrict__ Whh,
               const float* __restrict__ bih,
               const float* __restrict__ bhh,
               const float* __restrict__ Wlin,
               const float* __restrict__ blin,
               float* __restrict__ out,        // (T,B,H)
               float* __restrict__ lstm_out,   // (T,B,HIDN)  (STAGE==2 atomics)
               float* __restrict__ stage_f32,  // (T,B,H,HIDN)
               _Float16* __restrict__ stage_f16)
{
    const int lane = threadIdx.x;          // hidden unit index
    const int b    = blockIdx.x & (BB - 1);
    const int hd   = blockIdx.x >> 6;

    // ---- per-lane weights: the 4 gate rows of this unit, f16 in VGPRs ----
    h2 whh[4][HIDN / 2];
    h2 wih[4][II / 2];
    float bias[4];
#pragma unroll
    for (int g = 0; g < 4; ++g) {
        const int r = hd * GG + g * HIDN + lane;  // PyTorch gate-major row
        const float4* p = (const float4*)(Whh + (size_t)r * HIDN);
#pragma unroll
        for (int q = 0; q < HIDN / 4; ++q) {
            float4 v = p[q];
            whh[g][2 * q]     = h2{ (_Float16)v.x, (_Float16)v.y };
            whh[g][2 * q + 1] = h2{ (_Float16)v.z, (_Float16)v.w };
        }
        const float4* pi = (const float4*)(Wih + (size_t)r * II);
#pragma unroll
        for (int q = 0; q < II / 4; ++q) {
            float4 v = pi[q];
            wih[g][2 * q]     = h2{ (_Float16)v.x, (_Float16)v.y };
            wih[g][2 * q + 1] = h2{ (_Float16)v.z, (_Float16)v.w };
        }
        bias[g] = bih[r] + bhh[r];
    }
    const float wl = Wlin[hd * HIDN + lane];
    const float bl = blin[hd];

    __shared__ __align__(16) _Float16 hbuf[HIDN];  // 128 B, wave-synchronous
    hbuf[lane] = (_Float16)0.0f;   // in-order LDS pipe: visible to the reads below

    float c = 0.0f;

    const _Float16* xhp = xh + b * II;
    const float*    xfp = x + b * II;
    h2 xv[II / 2];
    auto load_x = [&](int t, h2* dst) {
        if (XF16) {
            const h8* p = (const h8*)(xhp + (size_t)t * BB * II);  // wave-uniform
            union { h8 v; h2 p2[4]; } u0, u1;
            u0.v = p[0];
            u1.v = p[1];
#pragma unroll
            for (int i = 0; i < 4; ++i) { dst[i] = u0.p2[i]; dst[4 + i] = u1.p2[i]; }
        } else {
            const float4* p = (const float4*)(xfp + (size_t)t * BB * II);
#pragma unroll
            for (int q = 0; q < 4; ++q) {
                float4 v = p[q];
                dst[2 * q]     = h2{ (_Float16)v.x, (_Float16)v.y };
                dst[2 * q + 1] = h2{ (_Float16)v.z, (_Float16)v.w };
            }
        }
    };
    load_x(0, xv);

    for (int t = 0; t < TT; ++t) {
        h2 xn[II / 2];
        if (t + 1 < TT) load_x(t + 1, xn);

        // broadcast-read h (conflict-free; 8 x ds_read_b128)
        union { h8 v[8]; h2 p[32]; } hr;
#pragma unroll
        for (int q = 0; q < 8; ++q) hr.v[q] = ((const h8*)hbuf)[q];

        // z_g = bias_g + W_hh[g,:].h + W_ih[g,:].x   (4 independent chains)
        float z0 = bias[0], z1 = bias[1], z2 = bias[2], z3 = bias[3];
#pragma unroll
        for (int q = 0; q < HIDN / 2; ++q) {
            z0 = fdot2(whh[0][q], hr.p[q], z0);
            z1 = fdot2(whh[1][q], hr.p[q], z1);
            z2 = fdot2(whh[2][q], hr.p[q], z2);
            z3 = fdot2(whh[3][q], hr.p[q], z3);
        }
#pragma unroll
        for (int q = 0; q < II / 2; ++q) {
            z0 = fdot2(wih[0][q], xv[q], z0);
            z1 = fdot2(wih[1][q], xv[q], z1);
            z2 = fdot2(wih[2][q], xv[q], z2);
            z3 = fdot2(wih[3][q], xv[q], z3);
        }

        float gi = fast_sigmoid(z0);
        float gf = fast_sigmoid(z1);
        float gg = fast_tanh(z2);
        float go = fast_sigmoid(z3);

        c = fmaf(gf, c, gi * gg);
        float h = go * fast_tanh(c);
        _Float16 h16 = (_Float16)h;

        // next step's h: in-order ds_write AFTER this step's reads (WAR safe,
        // single wave, no barrier)
        hbuf[lane] = h16;

        // fire-and-forget staging (no dependent wait in the loop)
        if (STAGE == 0) {
            stage_f32[(((size_t)t * BB + b) * HH + hd) * HIDN + lane] = h;
        } else if (STAGE == 1) {
            stage_f16[(((size_t)t * BB + b) * HH + hd) * HIDN + lane] = h16;
        } else {
            atomicAdd(&lstm_out[((size_t)t * BB + b) * HIDN + lane], h);
        }

        // out[t,b,hd] = dot(h, W_lin) + b_lin (off the recurrence path)
        float p = h * wl;
        p += __shfl_down(p, 32, 64);
        p += __shfl_down(p, 16, 64);
        p += __shfl_down(p, 8, 64);
        p += __shfl_down(p, 4, 64);
        p += __shfl_down(p, 2, 64);
        p += __shfl_down(p, 1, 64);
        if (lane == 0) out[((size_t)t * BB + b) * HH + hd] = p + bl;

#pragma unroll
        for (int q = 0; q < II / 2; ++q) xv[q] = xn[q];
    }
}

// ---------------- head-sum reduction (memory-bound) ----------------
template <bool F16>
__global__ void reduce_heads(const float* __restrict__ sf32,
                             const _Float16* __restrict__ sf16,
                             float* __restrict__ lstm_out)
{
    size_t j = (size_t)blockIdx.x * blockDim.x + threadIdx.x;  // 0 .. T*B*HIDN
    int k = (int)(j & (HIDN - 1));
    size_t tb = j >> 6;
    size_t base = tb * HH * HIDN + k;
    float s = 0.0f;
#pragma unroll
    for (int h = 0; h < HH; ++h)
        s += F16 ? (float)sf16[base + h * HIDN] : sf32[base + h * HIDN];
    lstm_out[j] = s;
}

extern "C" void kernel_launch(void* const* d_in, const int* in_sizes, int n_in,
                              void* d_out, int out_size, void* d_ws, size_t ws_size,
                              hipStream_t stream)
{
    const float* x    = (const float*)d_in[0];
    const float* Wih  = (const float*)d_in[1];
    const float* Whh  = (const float*)d_in[2];
    const float* bih  = (const float*)d_in[3];
    const float* bhh  = (const float*)d_in[4];
    const float* Wlin = (const float*)d_in[5];
    const float* blin = (const float*)d_in[6];

    float* out  = (float*)d_out;
    float* lstm = out + (size_t)TT * BB * HH;

    const size_t xbytes = (size_t)TT * BB * II * 2;          // 4 MB
    const size_t slab32 = (size_t)TT * BB * HH * HIDN * 4;   // 268 MB
    const size_t slab16 = slab32 / 2;                        // 134 MB

    const bool xf16 = ws_size >= xbytes;
    _Float16* xh = (_Float16*)d_ws;
    char* slabp  = (char*)d_ws + (xf16 ? xbytes : 0);
    size_t avail = ws_size - (xf16 ? xbytes : 0);
    const int mode = (avail >= slab32) ? 0 : (avail >= slab16 ? 1 : 2);

    if (xf16) {
        int n4 = TT * BB * II / 4;
        cvt_x_kernel<<<(n4 + 255) / 256, 256, 0, stream>>>(x, xh, n4);
    }
    if (mode == 2) {
        hipMemsetAsync(lstm, 0, (size_t)TT * BB * HIDN * 4, stream);
    }

    dim3 grid(BB * HH), block(64);
    float*    sf = (float*)slabp;
    _Float16* sh = (_Float16*)slabp;

#define LAUNCH_MAIN(M, XF) \
    lstm_wave<M, XF><<<grid, block, 0, stream>>>(x, xh, Wih, Whh, bih, bhh, Wlin, blin, out, lstm, sf, sh)

    if (xf16) {
        if (mode == 0)      LAUNCH_MAIN(0, true);
        else if (mode == 1) LAUNCH_MAIN(1, true);
        else                LAUNCH_MAIN(2, true);
    } else {
        if (mode == 0)      LAUNCH_MAIN(0, false);
        else if (mode == 1) LAUNCH_MAIN(1, false);
        else                LAUNCH_MAIN(2, false);
    }
#undef LAUNCH_MAIN

    if (mode == 0) {
        reduce_heads<false><<<(TT * BB * HIDN) / 256, 256, 0, stream>>>(sf, nullptr, lstm);
    } else if (mode == 1) {
        reduce_heads<true><<<(TT * BB * HIDN) / 256, 256, 0, stream>>>(nullptr, sh, lstm);
    }
}

// Round 4
// 1066.936 us; speedup vs baseline: 1.5861x; 1.5861x over previous
//
#include <hip/hip_runtime.h>
#include <hip/hip_fp16.h>

#define TT   2048
#define BB   64
#define II   16
#define HH   8
#define HIDN 64
#define GG   256   // 4*HIDN
#define T4   (TT / 4)

typedef _Float16 h2 __attribute__((ext_vector_type(2)));
typedef _Float16 h4 __attribute__((ext_vector_type(4)));
typedef _Float16 h8 __attribute__((ext_vector_type(8)));

__device__ __forceinline__ float fdot2(h2 a, h2 b, float c) {
    return __builtin_amdgcn_fdot2(a, b, c, false);
}
__device__ __forceinline__ float fast_sigmoid(float z) {
    return __builtin_amdgcn_rcpf(1.0f + __expf(-z));
}
__device__ __forceinline__ float fast_tanh(float z) {
    return fmaf(2.0f, __builtin_amdgcn_rcpf(1.0f + __expf(-2.0f * z)), -1.0f);
}

// ---------------- x -> f16 conversion (one-time, trivial) ----------------
__global__ void cvt_x_kernel(const float* __restrict__ x, _Float16* __restrict__ xh, int n4) {
    int i = blockIdx.x * blockDim.x + threadIdx.x;
    if (i < n4) {
        float4 v = ((const float4*)x)[i];
        ((h2*)xh)[2 * i]     = h2{ (_Float16)v.x, (_Float16)v.y };
        ((h2*)xh)[2 * i + 1] = h2{ (_Float16)v.z, (_Float16)v.w };
    }
}

// ---------------- main recurrent kernel: ONE WAVE PER CHAIN ----------------
// Latency-bound: total time = per-step critical path x 2048 (chains independent).
// Changes vs R3 (each removes a measured path component):
//  * __launch_bounds__(64,1): 512-VGPR budget -> weights stay in registers
//    (R3: VGPR_Count=140 < 160 needed => in-loop spill/remat).
//  * No W_lin/out in the loop (R3's 6 dependent ds_bpermutes serialized in the
//    in-order LDS pipe between h-write and next h-read).
//  * h staged to global every 4 steps (8B dwordx2, [t4][chain][unit][4] layout):
//    store acks retire before the in-order-vmcnt x-load wait reaches them.
template <int STAGE, bool XF16>   // STAGE 1: slab f16; STAGE 2: atomic fallback (out in-loop)
__global__ __launch_bounds__(64, 1)
void lstm_wave(const float* __restrict__ x,
               const _Float16* __restrict__ xh,
               const float* __restrict__ Wih,
               const float* __restrict__ Whh,
               const float* __restrict__ bih,
               const float* __restrict__ bhh,
               const float* __restrict__ Wlin,
               const float* __restrict__ blin,
               float* __restrict__ out,        // (T,B,H)      (STAGE==2 only)
               float* __restrict__ lstm_out,   // (T,B,HIDN)   (STAGE==2 atomics)
               _Float16* __restrict__ stage_f16)  // [T/4][512][64][4]
{
    const int lane = threadIdx.x;          // hidden unit index
    const int c    = blockIdx.x;           // chain id
    const int b    = c & (BB - 1);
    const int hd   = c >> 6;

    // ---- per-lane weights: the 4 gate rows of this unit, f16 in VGPRs ----
    h2 whh[4][HIDN / 2];
    h2 wih[4][II / 2];
    float bias[4];
#pragma unroll
    for (int g = 0; g < 4; ++g) {
        const int r = hd * GG + g * HIDN + lane;  // PyTorch gate-major row
        const float4* p = (const float4*)(Whh + (size_t)r * HIDN);
#pragma unroll
        for (int q = 0; q < HIDN / 4; ++q) {
            float4 v = p[q];
            whh[g][2 * q]     = h2{ (_Float16)v.x, (_Float16)v.y };
            whh[g][2 * q + 1] = h2{ (_Float16)v.z, (_Float16)v.w };
        }
        const float4* pi = (const float4*)(Wih + (size_t)r * II);
#pragma unroll
        for (int q = 0; q < II / 4; ++q) {
            float4 v = pi[q];
            wih[g][2 * q]     = h2{ (_Float16)v.x, (_Float16)v.y };
            wih[g][2 * q + 1] = h2{ (_Float16)v.z, (_Float16)v.w };
        }
        bias[g] = bih[r] + bhh[r];
    }
    float wl = 0.0f, bl = 0.0f;
    if (STAGE == 2) { wl = Wlin[hd * HIDN + lane]; bl = blin[hd]; }

    __shared__ __align__(16) _Float16 hbuf[HIDN];  // 128 B, wave-synchronous
    hbuf[lane] = (_Float16)0.0f;   // in-order LDS pipe: visible to reads below

    float cst = 0.0f;

    const _Float16* xhp = xh + b * II;
    const float*    xfp = x + b * II;
    h2 xv[II / 2];
    auto load_x = [&](int t, h2* dst) {
        int tc = t < TT ? t : TT - 1;   // branchless clamp (avoid OOB)
        if (XF16) {
            const h8* p = (const h8*)(xhp + (size_t)tc * BB * II);
            union { h8 v; h2 p2[4]; } u0, u1;
            u0.v = p[0];
            u1.v = p[1];
#pragma unroll
            for (int i = 0; i < 4; ++i) { dst[i] = u0.p2[i]; dst[4 + i] = u1.p2[i]; }
        } else {
            const float4* p = (const float4*)(xfp + (size_t)tc * BB * II);
#pragma unroll
            for (int q = 0; q < 4; ++q) {
                float4 v = p[q];
                dst[2 * q]     = h2{ (_Float16)v.x, (_Float16)v.y };
                dst[2 * q + 1] = h2{ (_Float16)v.z, (_Float16)v.w };
            }
        }
    };
    load_x(0, xv);

    // stage pointer: f16 index = t4*131072 + c*256 + lane*4 ; bump 131072/t4
    h4* sptr = (h4*)(stage_f16 + (size_t)c * 256 + lane * 4);

    for (int t4 = 0; t4 < T4; ++t4) {
        union { h4 v4; h2 p2[2]; } hp;
#pragma unroll
        for (int j = 0; j < 4; ++j) {
            const int t = t4 * 4 + j;
            h2 xn[II / 2];
            load_x(t + 1, xn);

            // broadcast-read h (8 x ds_read_b128, conflict-free)
            union { h8 v[8]; h2 p[32]; } hr;
#pragma unroll
            for (int q = 0; q < 8; ++q) hr.v[q] = ((const h8*)hbuf)[q];

            float z0 = bias[0], z1 = bias[1], z2 = bias[2], z3 = bias[3];
#pragma unroll
            for (int q = 0; q < HIDN / 2; ++q) {
                z0 = fdot2(whh[0][q], hr.p[q], z0);
                z1 = fdot2(whh[1][q], hr.p[q], z1);
                z2 = fdot2(whh[2][q], hr.p[q], z2);
                z3 = fdot2(whh[3][q], hr.p[q], z3);
            }
#pragma unroll
            for (int q = 0; q < II / 2; ++q) {
                z0 = fdot2(wih[0][q], xv[q], z0);
                z1 = fdot2(wih[1][q], xv[q], z1);
                z2 = fdot2(wih[2][q], xv[q], z2);
                z3 = fdot2(wih[3][q], xv[q], z3);
            }

            float gi = fast_sigmoid(z0);
            float gf = fast_sigmoid(z1);
            float gg = fast_tanh(z2);
            float go = fast_sigmoid(z3);

            cst = fmaf(gf, cst, gi * gg);
            float h = go * fast_tanh(cst);
            _Float16 h16 = (_Float16)h;

            hbuf[lane] = h16;            // in-order after this step's reads
            hp.p2[j >> 1][j & 1] = h16;  // compile-time lane-register pack

            if (STAGE == 2) {
                atomicAdd(&lstm_out[((size_t)t * BB + b) * HIDN + lane], h);
                float p = h * wl;
                p += __shfl_down(p, 32, 64);
                p += __shfl_down(p, 16, 64);
                p += __shfl_down(p, 8, 64);
                p += __shfl_down(p, 4, 64);
                p += __shfl_down(p, 2, 64);
                p += __shfl_down(p, 1, 64);
                if (lane == 0) out[((size_t)t * BB + b) * HH + hd] = p + bl;
            }

#pragma unroll
            for (int q = 0; q < II / 2; ++q) xv[q] = xn[q];
        }
        if (STAGE == 1) {
            *sptr = hp.v4;               // 8B fire-and-forget, acks amortized x4
            sptr += 512 * 64;            // 131072 f16 / 4 per h4
        }
    }
}

// ---------------- pass 2a: lstm_out[t,b,k] = sum_hd h ----------------
// block = (b, 64-t tile); 256 threads = (k, q). Coalesced reads & writes.
__global__ __launch_bounds__(256)
void pass_lstm(const _Float16* __restrict__ stage, float* __restrict__ lstm_out)
{
    const int tid  = threadIdx.x;
    const int k    = tid & (HIDN - 1);
    const int q    = tid >> 6;                 // 0..3
    const int b    = blockIdx.x & (BB - 1);
    const int tile = blockIdx.x >> 6;          // 0..31
    const h4* sp = (const h4*)stage;

#pragma unroll
    for (int g = 0; g < 4; ++g) {
        const int t4 = tile * 16 + q + 4 * g;
        float acc0 = 0.f, acc1 = 0.f, acc2 = 0.f, acc3 = 0.f;
#pragma unroll
        for (int hd = 0; hd < HH; ++hd) {
            h4 v = sp[((size_t)t4 * 512 + hd * 64 + b) * 64 + k];
            acc0 += (float)v.x; acc1 += (float)v.y;
            acc2 += (float)v.z; acc3 += (float)v.w;
        }
        const size_t t = (size_t)t4 * 4;
        lstm_out[((t + 0) * BB + b) * HIDN + k] = acc0;
        lstm_out[((t + 1) * BB + b) * HIDN + k] = acc1;
        lstm_out[((t + 2) * BB + b) * HIDN + k] = acc2;
        lstm_out[((t + 3) * BB + b) * HIDN + k] = acc3;
    }
}

// ---------------- pass 2b: out[t,b,hd] = dot(h, W_lin)+b_lin ----------------
// block = t4 (512 blocks), 512 threads = (b, hd) -> perfectly coalesced writes.
// Reads stride 512B/lane but k-loop reuses each 128B line 16x in L1.
__global__ __launch_bounds__(512)
void pass_out(const _Float16* __restrict__ stage,
              const float* __restrict__ Wlin,
              const float* __restrict__ blin,
              float* __restrict__ out)
{
    __shared__ float wls[GG * 2];   // 512 floats
    const int tid = threadIdx.x;
    wls[tid] = Wlin[tid];           // W_lin flat (8*64)
    __syncthreads();

    const int b  = tid >> 3;
    const int hd = tid & 7;
    const int c  = hd * 64 + b;
    const int t4 = blockIdx.x;
    const float bl = blin[hd];

    const h4* sp = (const h4*)stage + ((size_t)t4 * 512 + c) * 64;
    float a0 = 0.f, a1 = 0.f, a2 = 0.f, a3 = 0.f;
#pragma unroll 8
    for (int k = 0; k < HIDN; ++k) {
        h4 v = sp[k];
        float w = wls[hd * HIDN + k];
        a0 = fmaf((float)v.x, w, a0);
        a1 = fmaf((float)v.y, w, a1);
        a2 = fmaf((float)v.z, w, a2);
        a3 = fmaf((float)v.w, w, a3);
    }
    const size_t t = (size_t)t4 * 4;
    out[(t + 0) * 512 + tid] = a0 + bl;
    out[(t + 1) * 512 + tid] = a1 + bl;
    out[(t + 2) * 512 + tid] = a2 + bl;
    out[(t + 3) * 512 + tid] = a3 + bl;
}

extern "C" void kernel_launch(void* const* d_in, const int* in_sizes, int n_in,
                              void* d_out, int out_size, void* d_ws, size_t ws_size,
                              hipStream_t stream)
{
    const float* x    = (const float*)d_in[0];
    const float* Wih  = (const float*)d_in[1];
    const float* Whh  = (const float*)d_in[2];
    const float* bih  = (const float*)d_in[3];
    const float* bhh  = (const float*)d_in[4];
    const float* Wlin = (const float*)d_in[5];
    const float* blin = (const float*)d_in[6];

    float* out  = (float*)d_out;
    float* lstm = out + (size_t)TT * BB * HH;

    const size_t xbytes = (size_t)TT * BB * II * 2 + 4096;   // 4 MB + clamp slack
    const size_t slab16 = (size_t)TT * BB * HH * HIDN * 2;   // 134 MB

    const bool xf16 = ws_size >= xbytes;
    _Float16* xh = (_Float16*)d_ws;
    char* slabp  = (char*)d_ws + (xf16 ? xbytes : 0);
    size_t avail = ws_size - (xf16 ? xbytes : 0);
    const int mode = (avail >= slab16) ? 1 : 2;

    if (xf16) {
        int n4 = TT * BB * II / 4;
        cvt_x_kernel<<<(n4 + 255) / 256, 256, 0, stream>>>(x, xh, n4);
    }
    if (mode == 2) {
        hipMemsetAsync(lstm, 0, (size_t)TT * BB * HIDN * 4, stream);
    }

    dim3 grid(BB * HH), block(64);
    _Float16* sh = (_Float16*)slabp;

#define LAUNCH_MAIN(M, XF) \
    lstm_wave<M, XF><<<grid, block, 0, stream>>>(x, xh, Wih, Whh, bih, bhh, Wlin, blin, out, lstm, sh)

    if (xf16) { if (mode == 1) LAUNCH_MAIN(1, true);  else LAUNCH_MAIN(2, true); }
    else      { if (mode == 1) LAUNCH_MAIN(1, false); else LAUNCH_MAIN(2, false); }
#undef LAUNCH_MAIN

    if (mode == 1) {
        pass_lstm<<<dim3(BB * 32), dim3(256), 0, stream>>>(sh, lstm);
        pass_out <<<dim3(T4), dim3(512), 0, stream>>>(sh, Wlin, blin, out);
    }
}